// Round 9
// baseline (524.148 us; speedup 1.0000x reference)
//
#include <hip/hip_runtime.h>
#include <hip/hip_bf16.h>

#define B_ 4
#define U_ 16
#define L_ 128
#define H_ 768
#define M_ 256
#define HID_ 150

typedef _Float16 half8 __attribute__((ext_vector_type(8)));
typedef _Float16 half4t __attribute__((ext_vector_type(4)));
typedef float floatx4 __attribute__((ext_vector_type(4)));
typedef float floatx16 __attribute__((ext_vector_type(16)));

#define MFMA32(wf, af, acc) __builtin_amdgcn_mfma_f32_32x32x16_f16(wf, af, acc, 0, 0, 0)

union H8 { half8 v; half4t h[2]; };

// ---------------------------------------------------------------------------
// Kernel 0: fused prep (blocks 0..1539) + pool (blocks 1540..1795).
// Formats HW-verified R6/R7/R8 (absmax 0.0).
// ---------------------------------------------------------------------------
__global__ __launch_bounds__(256) void prep_pool_kernel(
    const float* __restrict__ W1, const float* __restrict__ W2,
    const float* __restrict__ b2, const float* __restrict__ W3,
    const float* __restrict__ hidden, const int* __restrict__ sutt,
    const int* __restrict__ sstart, const int* __restrict__ send,
    _Float16* __restrict__ W1cs, _Float16* __restrict__ W2s,
    _Float16* __restrict__ W1abs, float2* __restrict__ bw,
    _Float16* __restrict__ pooledh)
{
    if (blockIdx.x >= 1540) {   // ---- pool part ----
        const int bm = (blockIdx.x - 1540) * 4 + (threadIdx.x >> 6);
        const int lane = threadIdx.x & 63;
        const int b  = bm >> 8;
        const int u  = sutt[bm];
        const int st = sstart[bm];
        const int en = send[bm];
        const float inv = 1.0f / (float)(en - st);
        const float* src = hidden + ((size_t)(b * U_ + u) * L_) * H_ + lane * 12;
        float4 s[3];
        #pragma unroll
        for (int q = 0; q < 3; ++q) s[q] = make_float4(0.f, 0.f, 0.f, 0.f);
        for (int l = st; l < en; ++l) {
            const float* p = src + (size_t)l * H_;
            #pragma unroll
            for (int q = 0; q < 3; ++q) {
                float4 v = *(const float4*)(p + q * 4);
                s[q].x += v.x; s[q].y += v.y; s[q].z += v.z; s[q].w += v.w;
            }
        }
        _Float16* gp = pooledh + (size_t)bm * H_ + lane * 12;
        #pragma unroll
        for (int q = 0; q < 3; ++q) {
            half4t hv;
            hv[0] = (_Float16)(s[q].x * inv); hv[1] = (_Float16)(s[q].y * inv);
            hv[2] = (_Float16)(s[q].z * inv); hv[3] = (_Float16)(s[q].w * inv);
            *(half4t*)(gp + q * 4) = hv;
        }
        return;
    }
    // ---- prep part ----
    int idx = blockIdx.x * 256 + threadIdx.x;
    if (blockIdx.x == 0 && threadIdx.x < 160) {
        int n = threadIdx.x;
        bw[n] = (n < HID_) ? make_float2(b2[n], W3[n]) : make_float2(0.f, 0.f);
    }
    if (idx < 122880) {   // W1cs: idx = k*160 + n
        int k = idx / 160, n = idx - k * 160;
        float v = (n < HID_) ? W1[(size_t)(2 * H_ + k) * HID_ + n] : 0.f;
        W1cs[(k >> 4) * 2560 + (n >> 5) * 512 +
             (((n & 31) | (((k >> 3) & 1) << 5)) << 3) + (k & 7)] = (_Float16)v;
        return;
    }
    idx -= 122880;
    if (idx < 25600) {    // W2s
        int k = idx / 160, n = idx - k * 160;
        float v = (k < HID_ && n < HID_) ? W2[(size_t)k * HID_ + n] : 0.f;
        W2s[(k >> 4) * 2560 + (n >> 5) * 512 +
            (((n & 31) | (((k >> 3) & 1) << 5)) << 3) + (k & 7)] = (_Float16)v;
        return;
    }
    idx -= 25600;
    if (idx < 245760) {   // W1abs
        int k = idx / 320, n = idx - k * 320;
        float v = 0.f;
        if (n < HID_) v = W1[(size_t)k * HID_ + n];
        else if (n >= 160 && n < 160 + HID_) v = W1[(size_t)(H_ + k) * HID_ + (n - 160)];
        W1abs[(k >> 5) * 10240 + (n >> 4) * 512 +
              (((n & 15) | (((k >> 3) & 3) << 4)) << 3) + (k & 7)] = (_Float16)v;
    }
}

// ---------------------------------------------------------------------------
// Kernel 1: hi/hj projection, regridded (64 row-blocks x 4 n-quarters, 1 wave
// each) -- R8's 64-block version left 3/4 of the GPU idle.
// hiF[row][160] (b1 folded), hjT[160][1024]. Also zeroes the loss scalar.
// ---------------------------------------------------------------------------
__global__ __launch_bounds__(64) void hihj_kernel(
    const _Float16* __restrict__ pooledh, const float* __restrict__ b1,
    const _Float16* __restrict__ W1abs,
    float* __restrict__ hiF, float* __restrict__ hjT, float* __restrict__ out)
{
    if (blockIdx.x == 0 && blockIdx.y == 0 && threadIdx.x == 0) *out = 0.f;
    const int rowblk = blockIdx.x;       // 16 pooled rows
    const int nq     = blockIdx.y;       // 5 n-tiles
    const int lane = threadIdx.x & 63;
    const int g = lane >> 4, l15 = lane & 15;
    floatx4 acc[5];
    #pragma unroll
    for (int u5 = 0; u5 < 5; ++u5) acc[u5] = (floatx4){0.f, 0.f, 0.f, 0.f};
    const _Float16* aB = pooledh + (size_t)(rowblk * 16 + l15) * H_ + g * 8;
    for (int kc = 0; kc < 24; ++kc) {
        half8 av = *(const half8*)(aB + kc * 32);
        #pragma unroll
        for (int u5 = 0; u5 < 5; ++u5) {
            const int u = nq * 5 + u5;
            half8 bv = *(const half8*)(W1abs + (size_t)((kc * 20 + u) * 64 + lane) * 8);
            acc[u5] = __builtin_amdgcn_mfma_f32_16x16x32_f16(av, bv, acc[u5], 0, 0, 0);
        }
    }
    const int row0 = rowblk * 16 + g * 4;
    #pragma unroll
    for (int u5 = 0; u5 < 5; ++u5) {
        const int n = (nq * 5 + u5) * 16 + l15;
        if (n < HID_) {
            float b1v = b1[n];
            #pragma unroll
            for (int r = 0; r < 4; ++r)
                hiF[(size_t)(row0 + r) * 160 + n] = acc[u5][r] + b1v;
        } else if (n >= 160 && n < 160 + HID_) {
            *(float4*)&hjT[(size_t)(n - 160) * 1024 + row0] =
                make_float4(acc[u5][0], acc[u5][1], acc[u5][2], acc[u5][3]);
        }
    }
}

// ---------------------------------------------------------------------------
// Kernel 2: fused pair MLP, R=4 (wave owns 4 i-tiles x 32 j = 128 pairs).
// 1-wave blocks (barrier-free), 1 wave/SIMD (acc1 = 320 AGPR; R6 lesson),
// LDS 29.7 KB -> 4 blocks/CU.
// Per k-step: 20 MFMA (160 cyc) vs 5 KB weights (L1) + 1 LDS pj read + 4
// broadcast pi loads -> feed/compute balanced (R7 was 2x+ oversubscribed).
// pj staged per 64-K chunk in LDS dbuf via 4 coalesced loads (kills R7's
// per-kstep 32-line gathers). Rows stride 68 halves (136 B): bank step
// 2/row -> 2-way alias = free; b64-pair reads (b128 would misalign).
// h1: 2 tiles -> LDS (stride 164 halves = 328 B: bank step 18/row, 2-way),
// stage2 2 tiles/pass sharing W2 frags. C/D 32x32: col=lane&31,
// row=(reg&3)+8*(reg>>2)+4*(lane>>5).  [R4-verified]
// ---------------------------------------------------------------------------
__global__ __launch_bounds__(64, 1) void pair_mlp_kernel(
    const _Float16* __restrict__ pooledh,
    const float* __restrict__ hiF, const float* __restrict__ hjT,
    const _Float16* __restrict__ W1cs, const _Float16* __restrict__ W2s,
    const float2* __restrict__ bw, const float* __restrict__ b3,
    float* __restrict__ logits)
{
    __shared__ __align__(16) _Float16 pjL[2 * 32 * 68];    // 8704 B dbuf
    __shared__ __align__(16) _Float16 h1L[2 * 32 * 164];   // 20992 B

    // ---- block decode: 1152 blocks = 4 batches x 288 tiles (4i x 32j) ----
    int q = blockIdx.x;
    const int b = q / 288;
    int r = q - b * 288;
    int h = 0;
    while (r >= 8 * (h + 1)) { r -= 8 * (h + 1); ++h; }
    const int g = 8 * h + r / (h + 1);
    const int jt = r - (r / (h + 1)) * (h + 1);
    const int i0 = 4 * g, j0 = 32 * jt;
    const int bm = b * M_;
    const int lane = threadIdx.x & 63;
    const int c31 = lane & 31, hw = lane >> 5;

    floatx16 acc1[4][5];
    #pragma unroll
    for (int tt = 0; tt < 4; ++tt)
        #pragma unroll
        for (int t1 = 0; t1 < 5; ++t1)
            #pragma unroll
            for (int e = 0; e < 16; ++e) acc1[tt][t1][e] = 0.f;

    const int srow = j0 + (lane >> 3);           // staging row (lane>>3 in 0..7)
    const int sseg = (lane & 7) * 8;             // k-offset within chunk
    const _Float16* pjg = pooledh + (size_t)(bm + srow) * H_ + sseg;

    // ---- prologue: stage pj chunk 0 into buf 0 ----
    {
        half8 sj[4];
        #pragma unroll
        for (int q2 = 0; q2 < 4; ++q2)
            sj[q2] = *(const half8*)(pjg + (size_t)(q2 * 8) * H_);
        #pragma unroll
        for (int q2 = 0; q2 < 4; ++q2) {
            H8 u2; u2.v = sj[q2];
            _Float16* d = &pjL[((q2 * 8 + (lane >> 3))) * 68 + sseg];
            *(half4t*)d = u2.h[0];
            *(half4t*)(d + 4) = u2.h[1];
        }
    }

    // ---- stage 1: 12 chunks of K=64 ----
    #pragma unroll 2
    for (int c = 0; c < 12; ++c) {
        const int cur = c & 1;
        half8 sj[4];
        if (c < 11) {
            const int kb = (c + 1) * 64;
            #pragma unroll
            for (int q2 = 0; q2 < 4; ++q2)
                sj[q2] = *(const half8*)(pjg + (size_t)(q2 * 8) * H_ + kb);
        }
        #pragma unroll
        for (int ks = 0; ks < 4; ++ks) {
            H8 pj;
            const _Float16* rb = &pjL[cur * 2176 + c31 * 68 + ks * 16 + hw * 8];
            pj.h[0] = *(const half4t*)rb;
            pj.h[1] = *(const half4t*)(rb + 4);
            half8 prod[4];
            #pragma unroll
            for (int tt = 0; tt < 4; ++tt) {
                half8 pif = *(const half8*)(pooledh +
                    (size_t)(bm + i0 + tt) * H_ + c * 64 + ks * 16 + hw * 8);
                prod[tt] = pif * pj.v;
            }
            const _Float16* wb = W1cs + (size_t)(c * 4 + ks) * 2560 + lane * 8;
            #pragma unroll
            for (int t1 = 0; t1 < 5; ++t1) {
                half8 wf = *(const half8*)(wb + t1 * 512);
                acc1[0][t1] = MFMA32(wf, prod[0], acc1[0][t1]);
                acc1[1][t1] = MFMA32(wf, prod[1], acc1[1][t1]);
                acc1[2][t1] = MFMA32(wf, prod[2], acc1[2][t1]);
                acc1[3][t1] = MFMA32(wf, prod[3], acc1[3][t1]);
            }
        }
        if (c < 11) {
            _Float16* dbase = &pjL[(cur ^ 1) * 2176];
            #pragma unroll
            for (int q2 = 0; q2 < 4; ++q2) {
                H8 u2; u2.v = sj[q2];
                _Float16* d = dbase + (q2 * 8 + (lane >> 3)) * 68 + sseg;
                *(half4t*)d = u2.h[0];
                *(half4t*)(d + 4) = u2.h[1];
            }
        }
    }

    // ---- per 2-tile pass: epilogue1 -> LDS -> stage2 -> stage3 ----
    const float b3v = b3[0];
    #pragma unroll
    for (int tp = 0; tp < 2; ++tp) {
        // epilogue 1: h1 = relu(acc1 + hiF + hjT) for tiles 2tp, 2tp+1
        #pragma unroll
        for (int t1 = 0; t1 < 5; ++t1) {
            #pragma unroll
            for (int qd = 0; qd < 4; ++qd) {
                const int n1 = t1 * 32 + 8 * qd + 4 * hw;
                float hj0 = hjT[(size_t)(n1 + 0) * 1024 + bm + j0 + c31];
                float hj1 = hjT[(size_t)(n1 + 1) * 1024 + bm + j0 + c31];
                float hj2 = hjT[(size_t)(n1 + 2) * 1024 + bm + j0 + c31];
                float hj3 = hjT[(size_t)(n1 + 3) * 1024 + bm + j0 + c31];
                #pragma unroll
                for (int lt = 0; lt < 2; ++lt) {
                    const int tt = 2 * tp + lt;
                    float4 hiv = *(const float4*)&hiF[(size_t)(bm + i0 + tt) * 160 + n1];
                    half4t hv;
                    hv[0] = (_Float16)fmaxf(acc1[tt][t1][4 * qd + 0] + hiv.x + hj0, 0.f);
                    hv[1] = (_Float16)fmaxf(acc1[tt][t1][4 * qd + 1] + hiv.y + hj1, 0.f);
                    hv[2] = (_Float16)fmaxf(acc1[tt][t1][4 * qd + 2] + hiv.z + hj2, 0.f);
                    hv[3] = (_Float16)fmaxf(acc1[tt][t1][4 * qd + 3] + hiv.w + hj3, 0.f);
                    *(half4t*)&h1L[lt * 5248 + c31 * 164 + n1] = hv;
                }
            }
        }
        // stage 2: both tiles share each W2 fragment
        floatx16 acc2[2][5];
        #pragma unroll
        for (int lt = 0; lt < 2; ++lt)
            #pragma unroll
            for (int t2 = 0; t2 < 5; ++t2)
                #pragma unroll
                for (int e = 0; e < 16; ++e) acc2[lt][t2][e] = 0.f;
        #pragma unroll
        for (int kc2 = 0; kc2 < 10; ++kc2) {
            H8 hf[2];
            #pragma unroll
            for (int lt = 0; lt < 2; ++lt) {
                const _Float16* hb = &h1L[lt * 5248 + c31 * 164 + kc2 * 16 + hw * 8];
                hf[lt].h[0] = *(const half4t*)hb;
                hf[lt].h[1] = *(const half4t*)(hb + 4);
            }
            const _Float16* wb = W2s + (size_t)kc2 * 2560 + lane * 8;
            #pragma unroll
            for (int t2 = 0; t2 < 5; ++t2) {
                half8 wf = *(const half8*)(wb + t2 * 512);
                acc2[0][t2] = MFMA32(wf, hf[0].v, acc2[0][t2]);
                acc2[1][t2] = MFMA32(wf, hf[1].v, acc2[1][t2]);
            }
        }
        // stage 3
        #pragma unroll
        for (int lt = 0; lt < 2; ++lt) {
            float sown = 0.f;
            #pragma unroll
            for (int t2 = 0; t2 < 5; ++t2) {
                #pragma unroll
                for (int qd = 0; qd < 4; ++qd) {
                    const int n2 = t2 * 32 + 8 * qd + 4 * hw;
                    float4 bw01 = *(const float4*)&bw[n2];
                    float4 bw23 = *(const float4*)&bw[n2 + 2];
                    sown += fmaxf(acc2[lt][t2][4 * qd + 0] + bw01.x, 0.f) * bw01.y;
                    sown += fmaxf(acc2[lt][t2][4 * qd + 1] + bw01.z, 0.f) * bw01.w;
                    sown += fmaxf(acc2[lt][t2][4 * qd + 2] + bw23.x, 0.f) * bw23.y;
                    sown += fmaxf(acc2[lt][t2][4 * qd + 3] + bw23.z, 0.f) * bw23.w;
                }
            }
            float s = sown + __shfl_xor(sown, 32);
            const int i = i0 + 2 * tp + lt;
            const int j = j0 + c31;
            if (lane < 32 && j < i)
                logits[(size_t)(bm + i) * M_ + j] = s + b3v;
        }
    }
}

// ---------------------------------------------------------------------------
// Kernel 3: per-row softmax over j<=i, clipped label-mass NLL, atomic sum.
// ---------------------------------------------------------------------------
__global__ __launch_bounds__(256) void loss_kernel(
    const float* __restrict__ logits, const float* __restrict__ labels,
    float* __restrict__ out)
{
    const int bm = blockIdx.x;
    const int i  = bm & (M_ - 1);
    const int j  = threadIdx.x;
    __shared__ float red[4];
    __shared__ float bcast;

    float val = (j < i) ? logits[(size_t)bm * M_ + j]
                        : ((j == i) ? 0.0f : -1e30f);

    float m = val;
    #pragma unroll
    for (int off = 32; off >= 1; off >>= 1) m = fmaxf(m, __shfl_down(m, off, 64));
    const int wave = j >> 6, lane = j & 63;
    if (lane == 0) red[wave] = m;
    __syncthreads();
    if (j == 0) bcast = fmaxf(fmaxf(red[0], red[1]), fmaxf(red[2], red[3]));
    __syncthreads();
    const float mm = bcast;

    float e = (j <= i) ? expf(val - mm) : 0.0f;
    float s = e;
    #pragma unroll
    for (int off = 32; off >= 1; off >>= 1) s += __shfl_down(s, off, 64);
    __syncthreads();
    if (lane == 0) red[wave] = s;
    __syncthreads();
    if (j == 0) bcast = red[0] + red[1] + red[2] + red[3];
    __syncthreads();
    const float ssum = bcast;

    float prob = (j <= i) ? (e / ssum) : -1000.0f;
    float lab = labels[(size_t)bm * M_ + j];
    float tv = prob * lab;
    tv = fminf(fmaxf(tv, 1e-8f), 1.0f - 1e-8f);
    float rs = tv;
    #pragma unroll
    for (int off = 32; off >= 1; off >>= 1) rs += __shfl_down(rs, off, 64);
    __syncthreads();
    if (lane == 0) red[wave] = rs;
    __syncthreads();
    if (j == 0) atomicAdd(out, -logf(red[0] + red[1] + red[2] + red[3]));
}

// ---------------------------------------------------------------------------
extern "C" void kernel_launch(void* const* d_in, const int* in_sizes, int n_in,
                              void* d_out, int out_size, void* d_ws, size_t ws_size,
                              hipStream_t stream)
{
    const float* hidden = (const float*)d_in[0];
    const int*   sutt   = (const int*)d_in[1];
    const int*   sstart = (const int*)d_in[2];
    const int*   send   = (const int*)d_in[3];
    const float* labels = (const float*)d_in[4];
    const float* W1     = (const float*)d_in[5];
    const float* b1     = (const float*)d_in[6];
    const float* W2     = (const float*)d_in[7];
    const float* b2     = (const float*)d_in[8];
    const float* W3     = (const float*)d_in[9];
    const float* b3     = (const float*)d_in[10];

    float* ws = (float*)d_ws;
    float*    hiF     = ws;                          // [1024][160]
    float*    hjT     = ws + 163840;                 // [160][1024]
    float*    logits  = ws + 327680;                 // 262144
    float2*   bw      = (float2*)(ws + 589824);      // 160 float2
    _Float16* pooledh = (_Float16*)(ws + 590144);    // 786432 f16
    _Float16* W1cs    = (_Float16*)(ws + 983360);    // 122880 f16
    _Float16* W2s     = (_Float16*)(ws + 1106240);   // 25600 f16
    _Float16* W1abs   = (_Float16*)(ws + 1119040);   // 245760 f16
    float* out = (float*)d_out;

    prep_pool_kernel<<<dim3(1796), 256, 0, stream>>>(
        W1, W2, b2, W3, hidden, sutt, sstart, send,
        W1cs, W2s, W1abs, bw, pooledh);
    hihj_kernel<<<dim3(64, 4), 64, 0, stream>>>(pooledh, b1, W1abs, hiF, hjT, out);
    pair_mlp_kernel<<<dim3(1152), 64, 0, stream>>>(pooledh, hiF, hjT,
                                                   W1cs, W2s, bw, b3, logits);
    loss_kernel<<<dim3(B_ * M_), 256, 0, stream>>>(logits, labels, out);
}

// Round 10
// 229.994 us; speedup vs baseline: 2.2790x; 2.2790x over previous
//
#include <hip/hip_runtime.h>
#include <hip/hip_bf16.h>

#define B_ 4
#define U_ 16
#define L_ 128
#define H_ 768
#define M_ 256
#define HID_ 150

typedef _Float16 half8 __attribute__((ext_vector_type(8)));
typedef _Float16 half4t __attribute__((ext_vector_type(4)));
typedef float floatx4 __attribute__((ext_vector_type(4)));

#define MFMA16(af, bf, acc) __builtin_amdgcn_mfma_f32_16x16x32_f16(af, bf, acc, 0, 0, 0)

// ---------------------------------------------------------------------------
// Kernel 0: fused prep (blocks 0..1539) + pool (blocks 1540..1795).
// W1cs16 / W2s16 / W1abs all use the SAME 16x16 B-frag packing (HW-verified
// via hihj since R6): element (k,n) -> ((k>>5)*T + (n>>4))*512 +
// (((n&15)|(((k>>3)&3)<<4))<<3) + (k&7), T = tiles per kc32 row.
// Spot-checked: W1cs16 (k=17,n=37)->1321; W2s16 (k=40,n=3)->5272.
// ---------------------------------------------------------------------------
__global__ __launch_bounds__(256) void prep_pool_kernel(
    const float* __restrict__ W1, const float* __restrict__ W2,
    const float* __restrict__ b2, const float* __restrict__ W3,
    const float* __restrict__ hidden, const int* __restrict__ sutt,
    const int* __restrict__ sstart, const int* __restrict__ send,
    _Float16* __restrict__ W1cs, _Float16* __restrict__ W2s,
    _Float16* __restrict__ W1abs, float2* __restrict__ bw,
    _Float16* __restrict__ pooledh)
{
    if (blockIdx.x >= 1540) {   // ---- pool part ----
        const int bm = (blockIdx.x - 1540) * 4 + (threadIdx.x >> 6);
        const int lane = threadIdx.x & 63;
        const int b  = bm >> 8;
        const int u  = sutt[bm];
        const int st = sstart[bm];
        const int en = send[bm];
        const float inv = 1.0f / (float)(en - st);
        const float* src = hidden + ((size_t)(b * U_ + u) * L_) * H_ + lane * 12;
        float4 s[3];
        #pragma unroll
        for (int q = 0; q < 3; ++q) s[q] = make_float4(0.f, 0.f, 0.f, 0.f);
        for (int l = st; l < en; ++l) {
            const float* p = src + (size_t)l * H_;
            #pragma unroll
            for (int q = 0; q < 3; ++q) {
                float4 v = *(const float4*)(p + q * 4);
                s[q].x += v.x; s[q].y += v.y; s[q].z += v.z; s[q].w += v.w;
            }
        }
        _Float16* gp = pooledh + (size_t)bm * H_ + lane * 12;
        #pragma unroll
        for (int q = 0; q < 3; ++q) {
            half4t hv;
            hv[0] = (_Float16)(s[q].x * inv); hv[1] = (_Float16)(s[q].y * inv);
            hv[2] = (_Float16)(s[q].z * inv); hv[3] = (_Float16)(s[q].w * inv);
            *(half4t*)(gp + q * 4) = hv;
        }
        return;
    }
    // ---- prep part ----
    int idx = blockIdx.x * 256 + threadIdx.x;
    if (blockIdx.x == 0 && threadIdx.x < 160) {
        int n = threadIdx.x;
        bw[n] = (n < HID_) ? make_float2(b2[n], W3[n]) : make_float2(0.f, 0.f);
    }
    if (idx < 122880) {   // W1cs16: idx = k*160 + n (coalesced read over n)
        int k = idx / 160, n = idx - k * 160;
        float v = (n < HID_) ? W1[(size_t)(2 * H_ + k) * HID_ + n] : 0.f;
        W1cs[((k >> 5) * 10 + (n >> 4)) * 512 +
             (((n & 15) | (((k >> 3) & 3) << 4)) << 3) + (k & 7)] = (_Float16)v;
        return;
    }
    idx -= 122880;
    if (idx < 25600) {    // W2s16: idx = k*160 + n
        int k = idx / 160, n = idx - k * 160;
        float v = (k < HID_ && n < HID_) ? W2[(size_t)k * HID_ + n] : 0.f;
        W2s[((k >> 5) * 10 + (n >> 4)) * 512 +
            (((n & 15) | (((k >> 3) & 3) << 4)) << 3) + (k & 7)] = (_Float16)v;
        return;
    }
    idx -= 25600;
    if (idx < 245760) {   // W1abs: idx = k*320 + n (20 tiles per kc32)
        int k = idx / 320, n = idx - k * 320;
        float v = 0.f;
        if (n < HID_) v = W1[(size_t)k * HID_ + n];
        else if (n >= 160 && n < 160 + HID_) v = W1[(size_t)(H_ + k) * HID_ + (n - 160)];
        W1abs[(k >> 5) * 10240 + (n >> 4) * 512 +
              (((n & 15) | (((k >> 3) & 3) << 4)) << 3) + (k & 7)] = (_Float16)v;
    }
}

// ---------------------------------------------------------------------------
// Kernel 1: hi/hj projection, regridded (64 row-blocks x 4 n-quarters)
// [R9-verified]. NOW zero-pads hiF cols 150..159 and hjT rows 150..159 so
// pair_mlp's unguarded padded-n epilogue reads defined zeros.
// hiF[row][160] (b1 folded), hjT[160][1024]. Also zeroes the loss scalar.
// ---------------------------------------------------------------------------
__global__ __launch_bounds__(64) void hihj_kernel(
    const _Float16* __restrict__ pooledh, const float* __restrict__ b1,
    const _Float16* __restrict__ W1abs,
    float* __restrict__ hiF, float* __restrict__ hjT, float* __restrict__ out)
{
    if (blockIdx.x == 0 && blockIdx.y == 0 && threadIdx.x == 0) *out = 0.f;
    const int rowblk = blockIdx.x;       // 16 pooled rows
    const int nq     = blockIdx.y;       // 5 n-tiles
    const int lane = threadIdx.x & 63;
    const int g = lane >> 4, l15 = lane & 15;
    floatx4 acc[5];
    #pragma unroll
    for (int u5 = 0; u5 < 5; ++u5) acc[u5] = (floatx4){0.f, 0.f, 0.f, 0.f};
    const _Float16* aB = pooledh + (size_t)(rowblk * 16 + l15) * H_ + g * 8;
    for (int kc = 0; kc < 24; ++kc) {
        half8 av = *(const half8*)(aB + kc * 32);
        #pragma unroll
        for (int u5 = 0; u5 < 5; ++u5) {
            const int u = nq * 5 + u5;
            half8 bv = *(const half8*)(W1abs + (size_t)((kc * 20 + u) * 64 + lane) * 8);
            acc[u5] = MFMA16(av, bv, acc[u5]);
        }
    }
    const int row0 = rowblk * 16 + g * 4;
    #pragma unroll
    for (int u5 = 0; u5 < 5; ++u5) {
        const int n = (nq * 5 + u5) * 16 + l15;
        if (n < HID_) {
            float b1v = b1[n];
            #pragma unroll
            for (int r = 0; r < 4; ++r)
                hiF[(size_t)(row0 + r) * 160 + n] = acc[u5][r] + b1v;
        } else if (n < 160) {            // pad hiF cols 150..159 with zeros
            #pragma unroll
            for (int r = 0; r < 4; ++r)
                hiF[(size_t)(row0 + r) * 160 + n] = 0.f;
        } else if (n < 160 + HID_) {
            *(float4*)&hjT[(size_t)(n - 160) * 1024 + row0] =
                make_float4(acc[u5][0], acc[u5][1], acc[u5][2], acc[u5][3]);
        } else {                          // pad hjT rows 150..159 with zeros
            *(float4*)&hjT[(size_t)(n - 160) * 1024 + row0] =
                make_float4(0.f, 0.f, 0.f, 0.f);
        }
    }
}

// ---------------------------------------------------------------------------
// Kernel 2: fused pair MLP — m97-shaped. Block = 4 waves = 4 i x 32 j;
// wave = 1 i x 32 j = 2 m-tiles x 10 n-tiles of 16x16x32 -> acc = 80 regs
// (the R4/R6/R9 spill lesson: accumulator sets >240 regs are fatal).
// Stage1: W1c k64-chunk in LDS dbuf shared by 4 waves (L2 traffic /4);
// pj k64-chunk in padded LDS (stride 70: gcd(35,32)=1). 12 barriers/block,
// overlapped by ~3 resident blocks/CU (LDS 51.3 KB) — R6/R8 died at 1 blk/CU.
// h1 -> wave-private LDS rows (stride 170, R5-proven); stage2 A from LDS,
// B = W2s16 frags from hot L2, reused across both m-tiles.
// C/D 16x16: row=(lane>>4)*4+reg, col=lane&15 [hihj-verified].
// ---------------------------------------------------------------------------
__global__ __launch_bounds__(256, 2) void pair_mlp_kernel(
    const _Float16* __restrict__ pooledh,
    const float* __restrict__ hiF, const float* __restrict__ hjT,
    const _Float16* __restrict__ W1cs, const _Float16* __restrict__ W2s,
    const float2* __restrict__ bw, const float* __restrict__ b3,
    float* __restrict__ logits)
{
    // [0, 21760): union{ sW dbuf 2x10240 f16 | h1 128x170 f16 }
    // [21760, 26240): pjL dbuf 2 x 32x70 f16
    __shared__ __align__(16) _Float16 smem[26240];
    _Float16* pjL = smem + 21760;

    // ---- block decode (R9-verified): 1152 = 4 b x 288 (4i x 32j) tiles ----
    int q = blockIdx.x;
    const int b = q / 288;
    int r = q - b * 288;
    int h = 0;
    while (r >= 8 * (h + 1)) { r -= 8 * (h + 1); ++h; }
    const int gi = 8 * h + r / (h + 1);
    const int jt = r - (r / (h + 1)) * (h + 1);
    const int i0 = 4 * gi, j0 = 32 * jt;
    const int bm = b * M_;
    const int tid = threadIdx.x;
    const int w = tid >> 6, lane = tid & 63;
    const int g = lane >> 4, l15 = lane & 15;
    const int i = i0 + w;

    floatx4 acc[2][10];
    #pragma unroll
    for (int t = 0; t < 2; ++t)
        #pragma unroll
        for (int u = 0; u < 10; ++u) acc[t][u] = (floatx4){0.f, 0.f, 0.f, 0.f};

    const int prow = tid >> 3, pseg = tid & 7;     // pj staging coords
    const _Float16* pjg = pooledh + (size_t)(bm + j0 + prow) * H_ + pseg * 8;
    const _Float16* pip = pooledh + (size_t)(bm + i) * H_ + g * 8;

    // ---- prologue: stage chunk 0 (weights + pj) ----
    {
        half8 wst[5];
        #pragma unroll
        for (int q2 = 0; q2 < 5; ++q2)
            wst[q2] = *(const half8*)(W1cs + (size_t)(tid + q2 * 256) * 8);
        half8 pjst = *(const half8*)pjg;
        #pragma unroll
        for (int q2 = 0; q2 < 5; ++q2)
            *(half8*)&smem[(tid + q2 * 256) * 8] = wst[q2];
        *(half8*)&pjL[prow * 70 + pseg * 8] = pjst;
    }
    __syncthreads();

    // ---- stage 1: 12 k64 chunks ----
    for (int c = 0; c < 12; ++c) {
        const int cur = c & 1, nxt = cur ^ 1;
        half8 wst[5], pjn;
        if (c < 11) {
            const _Float16* wg = W1cs + (size_t)(c + 1) * 10240;
            #pragma unroll
            for (int q2 = 0; q2 < 5; ++q2)
                wst[q2] = *(const half8*)(wg + (size_t)(tid + q2 * 256) * 8);
            pjn = *(const half8*)(pjg + (c + 1) * 64);
        }
        #pragma unroll
        for (int ks = 0; ks < 2; ++ks) {
            half8 pif = *(const half8*)(pip + c * 64 + ks * 32);
            half8 a0 = *(const half8*)&pjL[cur * 2240 + l15 * 70 + ks * 32 + g * 8] * pif;
            half8 a1 = *(const half8*)&pjL[cur * 2240 + (16 + l15) * 70 + ks * 32 + g * 8] * pif;
            const _Float16* wb = &smem[cur * 10240 + ks * 5120 + lane * 8];
            #pragma unroll
            for (int u = 0; u < 10; ++u) {
                half8 bf = *(const half8*)(wb + u * 512);
                acc[0][u] = MFMA16(a0, bf, acc[0][u]);
                acc[1][u] = MFMA16(a1, bf, acc[1][u]);
            }
        }
        if (c < 11) {
            #pragma unroll
            for (int q2 = 0; q2 < 5; ++q2)
                *(half8*)&smem[nxt * 10240 + (tid + q2 * 256) * 8] = wst[q2];
            *(half8*)&pjL[nxt * 2240 + prow * 70 + pseg * 8] = pjn;
        }
        __syncthreads();
    }

    // ---- epilogue 1: h1 = relu(acc + hi + hj) -> wave-private LDS rows ----
    // (barrier above also guarantees all waves done reading sW before reuse)
    _Float16* h1w = smem + (size_t)(w * 32) * 170;
    #pragma unroll
    for (int u = 0; u < 10; ++u) {
        const int n = u * 16 + l15;                // 0..159, pads are zeroed
        float hiv = hiF[(size_t)(bm + i) * 160 + n];
        #pragma unroll
        for (int t = 0; t < 2; ++t) {
            float4 hjv = *(const float4*)&hjT[(size_t)n * 1024 + bm + j0 + t * 16 + g * 4];
            h1w[(t * 16 + g * 4 + 0) * 170 + n] =
                (_Float16)fmaxf(acc[t][u][0] + hiv + hjv.x, 0.f);
            h1w[(t * 16 + g * 4 + 1) * 170 + n] =
                (_Float16)fmaxf(acc[t][u][1] + hiv + hjv.y, 0.f);
            h1w[(t * 16 + g * 4 + 2) * 170 + n] =
                (_Float16)fmaxf(acc[t][u][2] + hiv + hjv.z, 0.f);
            h1w[(t * 16 + g * 4 + 3) * 170 + n] =
                (_Float16)fmaxf(acc[t][u][3] + hiv + hjv.w, 0.f);
        }
    }
    __syncthreads();   // cheap; orders ds_write -> ds_read (wave-private data)

    // ---- stage 2: h2pre = h1 @ W2 (A from LDS, B from hot L2, reuse x2) ----
    floatx4 acc2[2][10];
    #pragma unroll
    for (int t = 0; t < 2; ++t)
        #pragma unroll
        for (int u = 0; u < 10; ++u) acc2[t][u] = (floatx4){0.f, 0.f, 0.f, 0.f};

    for (int kc2 = 0; kc2 < 5; ++kc2) {
        half8 a20 = *(const half8*)&h1w[(0 * 16 + l15) * 170 + kc2 * 32 + g * 8];
        half8 a21 = *(const half8*)&h1w[(1 * 16 + l15) * 170 + kc2 * 32 + g * 8];
        const _Float16* w2b = W2s + (size_t)kc2 * 5120 + lane * 8;
        #pragma unroll
        for (int u = 0; u < 10; ++u) {
            half8 bf = *(const half8*)(w2b + u * 512);
            acc2[0][u] = MFMA16(a20, bf, acc2[0][u]);
            acc2[1][u] = MFMA16(a21, bf, acc2[1][u]);
        }
    }

    // ---- stage 3: s = relu(h2pre + b2) . W3 + b3 -> logits (j < i) ----
    const float b3v = b3[0];
    #pragma unroll
    for (int t = 0; t < 2; ++t) {
        float sr[4] = {0.f, 0.f, 0.f, 0.f};
        #pragma unroll
        for (int u = 0; u < 10; ++u) {
            const int n2 = u * 16 + l15;
            float2 bwv = bw[n2];
            #pragma unroll
            for (int r2 = 0; r2 < 4; ++r2)
                sr[r2] += fmaxf(acc2[t][u][r2] + bwv.x, 0.f) * bwv.y;
        }
        #pragma unroll
        for (int r2 = 0; r2 < 4; ++r2) {
            float s = sr[r2];
            s += __shfl_xor(s, 1);
            s += __shfl_xor(s, 2);
            s += __shfl_xor(s, 4);
            s += __shfl_xor(s, 8);
            if (l15 == 0) {
                const int j = j0 + t * 16 + g * 4 + r2;
                if (j < i)
                    logits[(size_t)(bm + i) * M_ + j] = s + b3v;
            }
        }
    }
}

// ---------------------------------------------------------------------------
// Kernel 3: per-row softmax over j<=i, clipped label-mass NLL, atomic sum.
// ---------------------------------------------------------------------------
__global__ __launch_bounds__(256) void loss_kernel(
    const float* __restrict__ logits, const float* __restrict__ labels,
    float* __restrict__ out)
{
    const int bm = blockIdx.x;
    const int i  = bm & (M_ - 1);
    const int j  = threadIdx.x;
    __shared__ float red[4];
    __shared__ float bcast;

    float val = (j < i) ? logits[(size_t)bm * M_ + j]
                        : ((j == i) ? 0.0f : -1e30f);

    float m = val;
    #pragma unroll
    for (int off = 32; off >= 1; off >>= 1) m = fmaxf(m, __shfl_down(m, off, 64));
    const int wave = j >> 6, lane = j & 63;
    if (lane == 0) red[wave] = m;
    __syncthreads();
    if (j == 0) bcast = fmaxf(fmaxf(red[0], red[1]), fmaxf(red[2], red[3]));
    __syncthreads();
    const float mm = bcast;

    float e = (j <= i) ? expf(val - mm) : 0.0f;
    float s = e;
    #pragma unroll
    for (int off = 32; off >= 1; off >>= 1) s += __shfl_down(s, off, 64);
    __syncthreads();
    if (lane == 0) red[wave] = s;
    __syncthreads();
    if (j == 0) bcast = red[0] + red[1] + red[2] + red[3];
    __syncthreads();
    const float ssum = bcast;

    float prob = (j <= i) ? (e / ssum) : -1000.0f;
    float lab = labels[(size_t)bm * M_ + j];
    float tv = prob * lab;
    tv = fminf(fmaxf(tv, 1e-8f), 1.0f - 1e-8f);
    float rs = tv;
    #pragma unroll
    for (int off = 32; off >= 1; off >>= 1) rs += __shfl_down(rs, off, 64);
    __syncthreads();
    if (lane == 0) red[wave] = rs;
    __syncthreads();
    if (j == 0) atomicAdd(out, -logf(red[0] + red[1] + red[2] + red[3]));
}

// ---------------------------------------------------------------------------
extern "C" void kernel_launch(void* const* d_in, const int* in_sizes, int n_in,
                              void* d_out, int out_size, void* d_ws, size_t ws_size,
                              hipStream_t stream)
{
    const float* hidden = (const float*)d_in[0];
    const int*   sutt   = (const int*)d_in[1];
    const int*   sstart = (const int*)d_in[2];
    const int*   send   = (const int*)d_in[3];
    const float* labels = (const float*)d_in[4];
    const float* W1     = (const float*)d_in[5];
    const float* b1     = (const float*)d_in[6];
    const float* W2     = (const float*)d_in[7];
    const float* b2     = (const float*)d_in[8];
    const float* W3     = (const float*)d_in[9];
    const float* b3     = (const float*)d_in[10];

    float* ws = (float*)d_ws;
    float*    hiF     = ws;                          // [1024][160]
    float*    hjT     = ws + 163840;                 // [160][1024]
    float*    logits  = ws + 327680;                 // 262144
    float2*   bw      = (float2*)(ws + 589824);      // 160 float2
    _Float16* pooledh = (_Float16*)(ws + 590144);    // 786432 f16
    _Float16* W1cs    = (_Float16*)(ws + 983360);    // 122880 f16 (16-pack)
    _Float16* W2s     = (_Float16*)(ws + 1106240);   // 25600 f16 (16-pack)
    _Float16* W1abs   = (_Float16*)(ws + 1119040);   // 245760 f16
    float* out = (float*)d_out;

    prep_pool_kernel<<<dim3(1796), 256, 0, stream>>>(
        W1, W2, b2, W3, hidden, sutt, sstart, send,
        W1cs, W2s, W1abs, bw, pooledh);
    hihj_kernel<<<dim3(64, 4), 64, 0, stream>>>(pooledh, b1, W1abs, hiF, hjT, out);
    pair_mlp_kernel<<<dim3(1152), 256, 0, stream>>>(pooledh, hiF, hjT,
                                                    W1cs, W2s, bw, b3, logits);
    loss_kernel<<<dim3(B_ * M_), 256, 0, stream>>>(logits, labels, out);
}